// Round 9
// baseline (1144.490 us; speedup 1.0000x reference)
//
#include <hip/hip_runtime.h>

typedef unsigned short u16;
typedef unsigned int u32;

#define N_NODES 100000
#define N_EDGES 50000
#define C 128
#define G_GEMM 1563               // ceil(100000/64) 64-row GEMM tiles-of-4-waves
#define NCNT (N_EDGES + N_NODES)  // 150000 combined key space (edges then nodes)
#define NBUCKC 1172               // ceil(150000 / 128) coarse buckets (key>>7)
#define BCHUNK 2048               // incidences per bucketize chunk
#define NBLK 1024                 // persistent grid: 4 blocks/CU (32KB LDS -> 5 max)

static __device__ __forceinline__ float bf2f(u16 h) {
    u32 u = ((u32)h) << 16;
    float f;
    __builtin_memcpy(&f, &u, 4);
    return f;
}

static __device__ __forceinline__ u16 f2bf(float f) {
    u32 u;
    __builtin_memcpy(&u, &f, 4);
    return (u16)((u + 0x7fffu + ((u >> 16) & 1u)) >> 16);  // RNE
}

typedef short s16x8 __attribute__((ext_vector_type(8)));
typedef float f32x4 __attribute__((ext_vector_type(4)));

struct MegaP {
    const float* x; const int* ni; const int* ei; const float* W; const float* bias;
    u16* Wt; u16* xw; u32* stage;
    u32* cntM; u32* offM; u32* bsum; uint2* rowinfo; u32* csrC; u16* ef;
    float* out;
    u32* bcnt; u32* bgen;
    int nnz, nb1, scanN, scanBlocks;
};

// Manual grid barrier (all NBLK blocks co-resident by capacity arithmetic).
// Dep-ordered RMWs (the "|(g>>31)" forces the gen-read to complete before the
// arrive/release issues); spin uses agent-scope atomic LOADS (no RMW storm);
// __threadfence = device-scope release/acquire (G16: cross-XCD visibility).
static __device__ __forceinline__ void gsync(u32* cnt, u32* gen) {
    __syncthreads();
    if (threadIdx.x == 0) {
        __threadfence();  // release prior writes
        u32 g = __hip_atomic_load(gen, __ATOMIC_ACQUIRE, __HIP_MEMORY_SCOPE_AGENT);
        u32 old = atomicAdd(cnt, 1u | (g >> 31));  // g>>31==0; creates dep on g
        if (old == NBLK - 1) {
            u32 z = atomicExch(cnt, 0u);           // reset BEFORE release
            atomicAdd(gen, 1u | (z >> 31));        // z>>31==0; dep on reset
        } else {
            u32 cur;
            do {
                __builtin_amdgcn_s_sleep(4);
                cur = __hip_atomic_load(gen, __ATOMIC_ACQUIRE,
                                        __HIP_MEMORY_SCOPE_AGENT);
            } while (cur == g);
        }
        __threadfence();  // acquire
    }
    __syncthreads();
}

// 8-wide branchless gather body (r6, unchanged)
#define GATHER8(SRC)                                                          \
    for (u32 base = 0; base < deg; base += 64) {                              \
        int m = (int)min(64u, deg - base);                                    \
        int myidx = (lane < m) ? (int)csr[start + base + lane] : 0;           \
        for (int t = 0; t < m; t += 8) {                                      \
            int i1 = min(t + 1, m - 1), i2 = min(t + 2, m - 1);               \
            int i3 = min(t + 3, m - 1), i4 = min(t + 4, m - 1);               \
            int i5 = min(t + 5, m - 1), i6 = min(t + 6, m - 1);               \
            int i7 = min(t + 7, m - 1);                                       \
            int r0 = __shfl(myidx, t),  r1 = __shfl(myidx, i1);               \
            int r2 = __shfl(myidx, i2), r3 = __shfl(myidx, i3);               \
            int r4 = __shfl(myidx, i4), r5 = __shfl(myidx, i5);               \
            int r6 = __shfl(myidx, i6), r7 = __shfl(myidx, i7);               \
            u32 u0 = ((const u32*)(SRC + (size_t)r0 * C))[lane];              \
            u32 u1 = ((const u32*)(SRC + (size_t)r1 * C))[lane];              \
            u32 u2 = ((const u32*)(SRC + (size_t)r2 * C))[lane];              \
            u32 u3 = ((const u32*)(SRC + (size_t)r3 * C))[lane];              \
            u32 u4 = ((const u32*)(SRC + (size_t)r4 * C))[lane];              \
            u32 u5 = ((const u32*)(SRC + (size_t)r5 * C))[lane];              \
            u32 u6 = ((const u32*)(SRC + (size_t)r6 * C))[lane];              \
            u32 u7 = ((const u32*)(SRC + (size_t)r7 * C))[lane];              \
            float k1 = (t + 1 < m) ? 1.f : 0.f, k2 = (t + 2 < m) ? 1.f : 0.f; \
            float k3 = (t + 3 < m) ? 1.f : 0.f, k4 = (t + 4 < m) ? 1.f : 0.f; \
            float k5 = (t + 5 < m) ? 1.f : 0.f, k6 = (t + 6 < m) ? 1.f : 0.f; \
            float k7 = (t + 7 < m) ? 1.f : 0.f;                               \
            ax += bf2f((u16)(u0 & 0xffffu)) + k1 * bf2f((u16)(u1 & 0xffffu))  \
                + k2 * bf2f((u16)(u2 & 0xffffu)) + k3 * bf2f((u16)(u3 & 0xffffu)) \
                + k4 * bf2f((u16)(u4 & 0xffffu)) + k5 * bf2f((u16)(u5 & 0xffffu)) \
                + k6 * bf2f((u16)(u6 & 0xffffu)) + k7 * bf2f((u16)(u7 & 0xffffu)); \
            ay += bf2f((u16)(u0 >> 16)) + k1 * bf2f((u16)(u1 >> 16))          \
                + k2 * bf2f((u16)(u2 >> 16)) + k3 * bf2f((u16)(u3 >> 16))     \
                + k4 * bf2f((u16)(u4 >> 16)) + k5 * bf2f((u16)(u5 >> 16))     \
                + k6 * bf2f((u16)(u6 >> 16)) + k7 * bf2f((u16)(u7 >> 16));    \
        }                                                                     \
    }

// One persistent kernel, 9 phases, 8 grid barriers. NO early returns anywhere
// (every block reaches every gsync). LDS: one 32 KB buffer re-purposed per
// phase (liveness separated by barriers).
__global__ __launch_bounds__(256, 4) void mega_k(MegaP p) {
    __shared__ __align__(16) float xs[64 * C];  // exactly 32 KB
    const int tid = threadIdx.x;
    const int blk = blockIdx.x;
    const int lane = tid & 63;
    const int wave = tid >> 6;

    // ---- P0: Wt[oc][k] = bf16(W[k][oc]) ----
    if (blk < 64) {
        int idx = blk * 256 + tid;
        int k = idx >> 7, oc = idx & 127;
        p.Wt[oc * 128 + k] = f2bf(p.W[k * 128 + oc]);
    }
    gsync(p.bcnt, p.bgen);

    // ---- P1: GEMM xw = bf16(x @ W), grid-stride over 1563 64-row tiles ----
    // LDS-staged A (global_load_lds w16); NEW: C-tile repacked through LDS,
    // stored as 4 coalesced dwordx4/thread (was 64 scattered 2B stores).
    {
        u16* ct = (u16*)xs;  // C-tile overlay (xs dead after A-frag convert)
        for (int b = blk; b < G_GEMM; b += NBLK) {
            size_t gbase = (size_t)b * 64 * C;
#pragma unroll
            for (int rnd = 0; rnd < 8; ++rnd) {
                int fl = rnd * 1024 + wave * 256 + lane * 4;
                int grow = b * 64 + (fl >> 7);
                const float* src = (grow < N_NODES) ? (p.x + gbase + fl) : p.x;
                __builtin_amdgcn_global_load_lds(
                    (const __attribute__((address_space(1))) void*)src,
                    (__attribute__((address_space(3))) void*)(xs + rnd * 1024 + wave * 256),
                    16, 0, 0);
            }
            __syncthreads();

            int tile = b * 4 + wave;
            int m = lane & 15, quad = lane >> 4;
            bool live = (tile < 6250);
            union { uint4 u; s16x8 v; } a[4];
            if (live) {
                const float* xr = xs + (wave * 16 + m) * C + quad * 8;
#pragma unroll
                for (int kk = 0; kk < 4; ++kk) {
                    float4 v0 = *(const float4*)(xr + kk * 32);
                    float4 v1 = *(const float4*)(xr + kk * 32 + 4);
                    a[kk].u.x = (u32)f2bf(v0.x) | ((u32)f2bf(v0.y) << 16);
                    a[kk].u.y = (u32)f2bf(v0.z) | ((u32)f2bf(v0.w) << 16);
                    a[kk].u.z = (u32)f2bf(v1.x) | ((u32)f2bf(v1.y) << 16);
                    a[kk].u.w = (u32)f2bf(v1.z) | ((u32)f2bf(v1.w) << 16);
                }
            }
            __syncthreads();  // xs (A) now dead for ALL waves -> ct may overwrite

            if (live) {
                f32x4 acc[8];
#pragma unroll
                for (int nt = 0; nt < 8; ++nt) acc[nt] = (f32x4){0.f, 0.f, 0.f, 0.f};
#pragma unroll
                for (int kk = 0; kk < 4; ++kk) {
                    int kb = kk * 32 + quad * 8;
#pragma unroll
                    for (int nt = 0; nt < 8; ++nt) {
                        union { uint4 u; s16x8 v; } bb;
                        bb.u = *(const uint4*)(p.Wt + (size_t)(nt * 16 + m) * C + kb);
                        acc[nt] = __builtin_amdgcn_mfma_f32_16x16x32_bf16(
                            a[kk].v, bb.v, acc[nt], 0, 0, 0);
                    }
                }
#pragma unroll
                for (int nt = 0; nt < 8; ++nt)
#pragma unroll
                    for (int r = 0; r < 4; ++r)
                        ct[(wave * 16 + quad * 4 + r) * C + nt * 16 + m] =
                            f2bf(acc[nt][r]);
            }
            __syncthreads();  // ct complete

            // coalesced C store: 16 KB = 4 rounds x 256 thr x 16 B
#pragma unroll
            for (int r = 0; r < 4; ++r) {
                int f = r * 2048 + tid * 8;  // u16 index into 64x128 ct
                int grow = b * 64 + (f >> 7);
                if (grow < N_NODES)
                    *(uint4*)(p.xw + (size_t)b * 64 * C + f) = *(const uint4*)(ct + f);
            }
            __syncthreads();  // before re-staging xs
        }
    }
    gsync(p.bcnt, p.bgen);

    // ---- P2: coarse bucket histogram (LDS atomics only) ----
    {
        u32* h = (u32*)xs;
        if (blk < p.nb1) {
            for (int b2 = tid; b2 < NBUCKC; b2 += 256) h[b2] = 0;
            __syncthreads();
            int i0 = blk * BCHUNK, iend = min(i0 + BCHUNK, p.nnz);
            for (int i = i0 + tid; i < iend; i += 256) {
                int e = p.ei[i], n = p.ni[i];
                atomicAdd(&h[e >> 7], 1u);
                atomicAdd(&h[(N_EDGES + n) >> 7], 1u);
            }
            __syncthreads();
            for (int b2 = tid; b2 < NBUCKC; b2 += 256)
                p.cntM[(size_t)b2 * p.nb1 + blk] = h[b2];
        }
    }
    gsync(p.bcnt, p.bgen);

    // ---- P3: exclusive scan of cntM (bucket-major) ----
    {
        u32* wsum = (u32*)xs;
        if (blk < p.scanBlocks) {
            int base = blk * 1024 + tid * 4;
            u32 v0 = 0, v1 = 0, v2 = 0, v3 = 0;
            if (base + 3 < p.scanN) {
                uint4 v = *(const uint4*)(p.cntM + base);
                v0 = v.x; v1 = v.y; v2 = v.z; v3 = v.w;
            } else {
                if (base + 0 < p.scanN) v0 = p.cntM[base + 0];
                if (base + 1 < p.scanN) v1 = p.cntM[base + 1];
                if (base + 2 < p.scanN) v2 = p.cntM[base + 2];
                if (base + 3 < p.scanN) v3 = p.cntM[base + 3];
            }
            u32 s = v0 + v1 + v2 + v3;
            u32 xv = s;
            for (int d = 1; d < 64; d <<= 1) {
                u32 y = __shfl_up(xv, (unsigned)d);
                if (lane >= d) xv += y;
            }
            if (lane == 63) wsum[wave] = xv;
            __syncthreads();
            u32 wo = 0;
            for (int w = 0; w < 4; ++w) wo += (w < wave) ? wsum[w] : 0u;
            u32 ex = wo + xv - s;
            if (base + 0 < p.scanN) p.offM[base + 0] = ex;
            if (base + 1 < p.scanN) p.offM[base + 1] = ex + v0;
            if (base + 2 < p.scanN) p.offM[base + 2] = ex + v0 + v1;
            if (base + 3 < p.scanN) p.offM[base + 3] = ex + v0 + v1 + v2;
            if (tid == 255) p.bsum[blk] = wo + xv;
        }
    }
    gsync(p.bcnt, p.bgen);

    // ---- P4: scan of block sums (block 0 only; scanBlocks <= 512) ----
    {
        u32* wsum = (u32*)xs;
        if (blk == 0) {
            int t = tid;
            u32 v0 = (2 * t < p.scanBlocks) ? p.bsum[2 * t] : 0u;
            u32 v1 = (2 * t + 1 < p.scanBlocks) ? p.bsum[2 * t + 1] : 0u;
            u32 s = v0 + v1, xv = s;
            for (int d = 1; d < 64; d <<= 1) {
                u32 y = __shfl_up(xv, (unsigned)d);
                if (lane >= d) xv += y;
            }
            if (lane == 63) wsum[wave] = xv;
            __syncthreads();
            u32 wo = 0;
            for (int w = 0; w < 4; ++w) wo += (w < wave) ? wsum[w] : 0u;
            u32 ex = wo + xv - s;
            if (2 * t < p.scanBlocks) p.bsum[2 * t] = ex;
            if (2 * t + 1 < p.scanBlocks) p.bsum[2 * t + 1] = ex + v0;
        }
    }
    gsync(p.bcnt, p.bgen);

    // ---- P5: place entries bucket-grouped (LDS cursors only) ----
    {
        u32* cur = (u32*)xs;
        if (blk < p.nb1) {
            for (int b2 = tid; b2 < NBUCKC; b2 += 256) {
                size_t idx = (size_t)b2 * p.nb1 + blk;
                cur[b2] = p.offM[idx] + p.bsum[idx >> 10];
            }
            __syncthreads();
            int i0 = blk * BCHUNK, iend = min(i0 + BCHUNK, p.nnz);
            for (int i = i0 + tid; i < iend; i += 256) {
                int e = p.ei[i], n = p.ni[i];
                u32 p1 = atomicAdd(&cur[e >> 7], 1u);
                p.stage[p1] = ((u32)(e & 127) << 17) | (u32)n;
                int k2 = N_EDGES + n;
                u32 p2 = atomicAdd(&cur[k2 >> 7], 1u);
                p.stage[p2] = ((u32)(k2 & 127) << 17) | (u32)e;
            }
        }
    }
    gsync(p.bcnt, p.bgen);

    // ---- P6: per-bucket fine counting-sort -> dense CSR + rowinfo ----
    {
        u32* h2 = (u32*)xs;
        u32* ks = h2 + 128;
        for (int b = blk; b < NBUCKC; b += NBLK) {
            size_t i0 = (size_t)b * p.nb1;
            u32 gstart = p.offM[i0] + p.bsum[i0 >> 10];
            u32 gend;
            if (b + 1 < NBUCKC) {
                size_t i1 = (size_t)(b + 1) * p.nb1;
                gend = p.offM[i1] + p.bsum[i1 >> 10];
            } else {
                gend = (u32)(2 * p.nnz);
            }
            int sz = (int)(gend - gstart);
            if (tid < 128) h2[tid] = 0;
            __syncthreads();
            for (int i = tid; i < sz; i += 256)
                atomicAdd(&h2[p.stage[gstart + i] >> 17], 1u);
            __syncthreads();
            if (tid < 64) {
                int l = tid;
                u32 s0 = h2[2 * l], s1 = h2[2 * l + 1];
                u32 ps = s0 + s1, xv = ps;
                for (int d = 1; d < 64; d <<= 1) {
                    u32 y = __shfl_up(xv, (unsigned)d);
                    if (l >= d) xv += y;
                }
                u32 ex = xv - ps;
                ks[2 * l] = ex;
                ks[2 * l + 1] = ex + s0;
                int gk = b * 128 + 2 * l;
                if (gk < NCNT) p.rowinfo[gk] = make_uint2(gstart + ex, s0);
                if (gk + 1 < NCNT) p.rowinfo[gk + 1] = make_uint2(gstart + ex + s0, s1);
            }
            __syncthreads();
            for (int i = tid; i < sz; i += 256) {
                u32 en = p.stage[gstart + i];
                u32 kl = en >> 17;
                u32 pp = atomicAdd(&ks[kl], 1u);
                p.csrC[gstart + pp] = en & 0x1FFFFu;
            }
            __syncthreads();
        }
    }
    gsync(p.bcnt, p.bgen);

    // ---- P7: edge gather, 1 edge/wave grid-stride ----
    {
        const u32* csr = p.csrC;
        int gw = blk * 4 + wave;
        for (int e = gw; e < N_EDGES; e += NBLK * 4) {
            uint2 ri = p.rowinfo[e];
            u32 deg = ri.y;
            u32 start = ri.x;
            float ax = 0.f, ay = 0.f;
            GATHER8(p.xw)
            float sc = deg ? 1.f / (float)deg : 0.f;
            ((u32*)(p.ef + (size_t)e * C))[lane] =
                (u32)f2bf(ax * sc) | ((u32)f2bf(ay * sc) << 16);
        }
    }
    gsync(p.bcnt, p.bgen);

    // ---- P8: node gather, 1 node/wave grid-stride ----
    {
        const u32* csr = p.csrC;
        int gw = blk * 4 + wave;
        float b0 = p.bias[2 * lane], b1 = p.bias[2 * lane + 1];
        for (int v = gw; v < N_NODES; v += NBLK * 4) {
            uint2 ri = p.rowinfo[N_EDGES + v];
            u32 deg = ri.y;
            u32 start = ri.x;
            float ax = 0.f, ay = 0.f;
            GATHER8(p.ef)
            float sc = deg ? 1.f / (float)deg : 0.f;
            float2 r;
            r.x = ax * sc + b0;
            r.y = ay * sc + b1;
            ((float2*)(p.out + (size_t)v * C))[lane] = r;
        }
    }
}

extern "C" void kernel_launch(void* const* d_in, const int* in_sizes, int n_in,
                              void* d_out, int out_size, void* d_ws, size_t ws_size,
                              hipStream_t stream) {
    const float* x = (const float*)d_in[0];     // [N_NODES,128] f32
    const int* node_idx = (const int*)d_in[1];  // [2, NNZ] row-major int32
    const int nnz = in_sizes[1] / 2;
    const int* edge_idx = node_idx + nnz;
    const float* W = (const float*)d_in[2];     // [128,128] f32
    const float* bias = (const float*)d_in[3];  // [128] f32
    float* out = (float*)d_out;                 // [N_NODES,128] f32

    int nb1 = (nnz + BCHUNK - 1) / BCHUNK;      // 245
    int scanN = NBUCKC * nb1;                   // 287140
    int scanBlocks = (scanN + 1023) / 1024;     // 281 (<= 512 for P4)

    // workspace layout (~20.3 MB), all 16B-aligned:
    u16* Wt = (u16*)d_ws;                           // 32 KB
    u16* ef = Wt + 16384;                           // 12.8 MB
    u32* cntM = (u32*)(ef + (size_t)N_EDGES * C);   // scanN u32
    u32* offM = cntM + scanN;                       // scanN u32
    u32* bsum2 = offM + scanN;                      // 512 u32
    uint2* rowinfo = (uint2*)(bsum2 + 512);         // 150000 uint2
    u32* csrC = (u32*)(rowinfo + NCNT);             // 2*nnz u32
    u32* bar = csrC + 2 * (size_t)nnz;              // barrier: cnt@0, gen@64

    // d_out (51.2 MB f32) doubles as scratch:
    //   [0, 25.6 MB):    xw bf16        — consumed by P7
    //   [25.6, 29.6 MB): stage (packed) — written P5, consumed P6
    //   (P1 tail-block scribble into stage region predates P5 — harmless.)
    // P8 then overwrites the whole buffer with the f32 output.
    u16* xw = (u16*)d_out;
    u32* stage = (u32*)((char*)d_out + (size_t)N_NODES * C * 2);

    hipMemsetAsync(bar, 0, 256, stream);

    MegaP p;
    p.x = x; p.ni = node_idx; p.ei = edge_idx; p.W = W; p.bias = bias;
    p.Wt = Wt; p.xw = xw; p.stage = stage;
    p.cntM = cntM; p.offM = offM; p.bsum = bsum2; p.rowinfo = rowinfo;
    p.csrC = csrC; p.ef = ef; p.out = out;
    p.bcnt = bar; p.bgen = bar + 64;
    p.nnz = nnz; p.nb1 = nb1; p.scanN = scanN; p.scanBlocks = scanBlocks;

    mega_k<<<NBLK, 256, 0, stream>>>(p);
}

// Round 10
// 212.932 us; speedup vs baseline: 5.3749x; 5.3749x over previous
//
#include <hip/hip_runtime.h>

typedef unsigned short u16;
typedef unsigned int u32;

#define N_NODES 100000
#define N_EDGES 50000
#define C 128
#define G_GEMM 1563               // ceil(100000/64) 64-row GEMM blocks
#define NCNT (N_EDGES + N_NODES)  // 150000 combined key space (edges then nodes)
#define NBUCKC 1172               // ceil(150000 / 128) coarse buckets (key>>7)
#define BCHUNK 2048               // incidences per bucketize block

static __device__ __forceinline__ float bf2f(u16 h) {
    u32 u = ((u32)h) << 16;
    float f;
    __builtin_memcpy(&f, &u, 4);
    return f;
}

static __device__ __forceinline__ u16 f2bf(float f) {
    u32 u;
    __builtin_memcpy(&u, &f, 4);
    return (u16)((u + 0x7fffu + ((u >> 16) & 1u)) >> 16);  // RNE
}

typedef short s16x8 __attribute__((ext_vector_type(8)));
typedef float f32x4 __attribute__((ext_vector_type(4)));

// ---------------- W transpose -> bf16: Wt[oc][k] = bf16(W[k][oc]) ----------
__global__ void transpose_w(const float* __restrict__ W, u16* __restrict__ Wt) {
    int idx = blockIdx.x * 256 + threadIdx.x;  // 16384 total
    int k = idx >> 7, oc = idx & 127;
    Wt[oc * 128 + k] = f2bf(W[k * 128 + oc]);
}

// ---------------- GEMM: LDS-staged A + LDS-repacked coalesced C store ------
// r8 LDS staging kept (null but harmless); NEW (r10): C-tile repacked
// through the dead A-buffer and stored as 4x16B per thread instead of 32
// scattered 2B stores per lane (store-issue savings).
// xw[n][oc] = x[n][:] . W[:][oc], bf16 out. One wave per 16-row tile;
// A[m=lane&15][k=quad*8+j]; D col=lane&15, row=quad*4+reg (verified m89/m91).
__global__ __launch_bounds__(256) void gemm_k(
    const float* __restrict__ x, const u16* __restrict__ Wt,
    u16* __restrict__ xw) {
    __shared__ __align__(16) float xs[64 * C];  // 32 KB
    int tid = threadIdx.x;
    int blk = blockIdx.x;
    int lane = tid & 63;
    int wave = tid >> 6;

    // stage: 8 rounds x (256 thr x 16 B) = 32 KB; LDS dest = wave-uniform
    // base + lane*16 (HW rule); global src per-lane, tail rows redirected.
    size_t gbase = (size_t)blk * 64 * C;
#pragma unroll
    for (int rnd = 0; rnd < 8; ++rnd) {
        int fl = rnd * 1024 + wave * 256 + lane * 4;
        int grow = blk * 64 + (fl >> 7);
        const float* src = (grow < N_NODES) ? (x + gbase + fl) : x;
        __builtin_amdgcn_global_load_lds(
            (const __attribute__((address_space(1))) void*)src,
            (__attribute__((address_space(3))) void*)(xs + rnd * 1024 + wave * 256),
            16, 0, 0);
    }
    __syncthreads();

    int tile = blk * 4 + wave;
    int m = lane & 15;
    int quad = lane >> 4;
    bool live = (tile < 6250);

    union { uint4 u; s16x8 v; } a[4];
    if (live) {
        const float* xr = xs + (wave * 16 + m) * C + quad * 8;
#pragma unroll
        for (int kk = 0; kk < 4; ++kk) {
            float4 v0 = *(const float4*)(xr + kk * 32);
            float4 v1 = *(const float4*)(xr + kk * 32 + 4);
            a[kk].u.x = (u32)f2bf(v0.x) | ((u32)f2bf(v0.y) << 16);
            a[kk].u.y = (u32)f2bf(v0.z) | ((u32)f2bf(v0.w) << 16);
            a[kk].u.z = (u32)f2bf(v1.x) | ((u32)f2bf(v1.y) << 16);
            a[kk].u.w = (u32)f2bf(v1.z) | ((u32)f2bf(v1.w) << 16);
        }
    }
    __syncthreads();  // A reads done for ALL waves -> ct overlay may overwrite

    u16* ct = (u16*)xs;  // 16 KB C-tile overlay
    if (live) {
        f32x4 acc[8];
#pragma unroll
        for (int nt = 0; nt < 8; ++nt) acc[nt] = (f32x4){0.f, 0.f, 0.f, 0.f};
#pragma unroll
        for (int kk = 0; kk < 4; ++kk) {
            int kb = kk * 32 + quad * 8;
#pragma unroll
            for (int nt = 0; nt < 8; ++nt) {
                union { uint4 u; s16x8 v; } b;
                b.u = *(const uint4*)(Wt + (size_t)(nt * 16 + m) * C + kb);
                acc[nt] = __builtin_amdgcn_mfma_f32_16x16x32_bf16(a[kk].v, b.v, acc[nt], 0, 0, 0);
            }
        }
#pragma unroll
        for (int nt = 0; nt < 8; ++nt)
#pragma unroll
            for (int r = 0; r < 4; ++r)
                ct[(wave * 16 + quad * 4 + r) * C + nt * 16 + m] = f2bf(acc[nt][r]);
    }
    __syncthreads();  // ct complete

    // coalesced C store: 16 KB = 4 rounds x 256 thr x 16 B
#pragma unroll
    for (int r = 0; r < 4; ++r) {
        int f = r * 2048 + tid * 8;  // u16 index into 64x128 ct
        int grow = blk * 64 + (f >> 7);
        if (grow < N_NODES)
            *(uint4*)(xw + (size_t)blk * 64 * C + f) = *(const uint4*)(ct + f);
    }
}

// ---------------- P1a: per-(block,bucket) counts — ZERO global atomics -----
__global__ __launch_bounds__(256) void bucket_hist_k(
    const int* __restrict__ ni, const int* __restrict__ ei,
    u32* __restrict__ cntM, int nnz, int nb1) {
    __shared__ u32 h[NBUCKC];
    for (int b = threadIdx.x; b < NBUCKC; b += 256) h[b] = 0;
    __syncthreads();
    int i0 = blockIdx.x * BCHUNK;
    int iend = min(i0 + BCHUNK, nnz);
    for (int i = i0 + threadIdx.x; i < iend; i += 256) {
        int e = ei[i], n = ni[i];
        atomicAdd(&h[e >> 7], 1u);                 // LDS atomic (fast)
        atomicAdd(&h[(N_EDGES + n) >> 7], 1u);
    }
    __syncthreads();
    for (int b = threadIdx.x; b < NBUCKC; b += 256)
        cntM[(size_t)b * nb1 + blockIdx.x] = h[b];  // plain stores
}

// ---------------- scan A: generic exclusive scan ---------------------------
__global__ __launch_bounds__(256) void scan_a2(const u32* __restrict__ cnt,
                                               u32* __restrict__ off,
                                               u32* __restrict__ bsum, int N) {
    __shared__ u32 wsum[4];
    int tid = threadIdx.x;
    int base = blockIdx.x * 1024 + tid * 4;
    u32 v0 = 0, v1 = 0, v2 = 0, v3 = 0;
    if (base + 3 < N) {
        uint4 v = *(const uint4*)(cnt + base);
        v0 = v.x; v1 = v.y; v2 = v.z; v3 = v.w;
    } else {
        if (base + 0 < N) v0 = cnt[base + 0];
        if (base + 1 < N) v1 = cnt[base + 1];
        if (base + 2 < N) v2 = cnt[base + 2];
        if (base + 3 < N) v3 = cnt[base + 3];
    }
    u32 s = v0 + v1 + v2 + v3;
    int lane = tid & 63, wv = tid >> 6;
    u32 x = s;
    for (int d = 1; d < 64; d <<= 1) {
        u32 y = __shfl_up(x, (unsigned)d);
        if (lane >= d) x += y;
    }
    if (lane == 63) wsum[wv] = x;
    __syncthreads();
    u32 wo = 0;
    for (int w = 0; w < 4; ++w) wo += (w < wv) ? wsum[w] : 0u;
    u32 ex = wo + x - s;
    if (base + 0 < N) off[base + 0] = ex;
    if (base + 1 < N) off[base + 1] = ex + v0;
    if (base + 2 < N) off[base + 2] = ex + v0 + v1;
    if (base + 3 < N) off[base + 3] = ex + v0 + v1 + v2;
    if (tid == 255) bsum[blockIdx.x] = wo + x;  // block total
}

// ---------------- scan B: exclusive scan of up to 512 block sums ----------
__global__ __launch_bounds__(256) void scan_b2(u32* __restrict__ bsum, int nb) {
    __shared__ u32 wsum[4];
    int t = threadIdx.x;
    u32 v0 = (2 * t < nb) ? bsum[2 * t] : 0u;
    u32 v1 = (2 * t + 1 < nb) ? bsum[2 * t + 1] : 0u;
    u32 s = v0 + v1;
    int lane = t & 63, wv = t >> 6;
    u32 x = s;
    for (int d = 1; d < 64; d <<= 1) {
        u32 y = __shfl_up(x, (unsigned)d);
        if (lane >= d) x += y;
    }
    if (lane == 63) wsum[wv] = x;
    __syncthreads();
    u32 wo = 0;
    for (int w = 0; w < 4; ++w) wo += (w < wv) ? wsum[w] : 0u;
    u32 ex = wo + x - s;
    if (2 * t < nb) bsum[2 * t] = ex;
    if (2 * t + 1 < nb) bsum[2 * t + 1] = ex + v0;
}

// ---------------- P1b: place entries bucket-grouped (LDS cursors only) -----
__global__ __launch_bounds__(256) void bucket_place_k(
    const int* __restrict__ ni, const int* __restrict__ ei,
    const u32* __restrict__ offM, const u32* __restrict__ bsum,
    u32* __restrict__ stage, int nnz, int nb1) {
    __shared__ u32 cur[NBUCKC];
    for (int b = threadIdx.x; b < NBUCKC; b += 256) {
        size_t idx = (size_t)b * nb1 + blockIdx.x;
        cur[b] = offM[idx] + bsum[idx >> 10];
    }
    __syncthreads();
    int i0 = blockIdx.x * BCHUNK;
    int iend = min(i0 + BCHUNK, nnz);
    for (int i = i0 + threadIdx.x; i < iend; i += 256) {
        int e = ei[i], n = ni[i];
        u32 p1 = atomicAdd(&cur[e >> 7], 1u);
        stage[p1] = ((u32)(e & 127) << 17) | (u32)n;
        int k2 = N_EDGES + n;
        u32 p2 = atomicAdd(&cur[k2 >> 7], 1u);
        stage[p2] = ((u32)(k2 & 127) << 17) | (u32)e;
    }
}

// ---------------- P2: per-bucket fine counting-sort -> dense CSR + rowinfo --
__global__ __launch_bounds__(256) void bucket_csr_k(
    const u32* __restrict__ offM, const u32* __restrict__ bsum,
    const u32* __restrict__ stage, u32* __restrict__ csr,
    uint2* __restrict__ rowinfo, int nnz, int nb1) {
    __shared__ u32 h[128];
    __shared__ u32 ks[128];
    int b = blockIdx.x;
    size_t i0 = (size_t)b * nb1;
    u32 gstart = offM[i0] + bsum[i0 >> 10];
    u32 gend;
    if (b + 1 < NBUCKC) {
        size_t i1 = (size_t)(b + 1) * nb1;
        gend = offM[i1] + bsum[i1 >> 10];
    } else {
        gend = (u32)(2 * nnz);
    }
    int size = (int)(gend - gstart);
    if (threadIdx.x < 128) h[threadIdx.x] = 0;
    __syncthreads();
    for (int i = threadIdx.x; i < size; i += 256)
        atomicAdd(&h[stage[gstart + i] >> 17], 1u);
    __syncthreads();
    if (threadIdx.x < 64) {
        int l = threadIdx.x;
        u32 s0 = h[2 * l], s1 = h[2 * l + 1];
        u32 ps = s0 + s1;
        u32 x = ps;
        for (int d = 1; d < 64; d <<= 1) {
            u32 y = __shfl_up(x, (unsigned)d);
            if (l >= d) x += y;
        }
        u32 ex = x - ps;  // exclusive pair prefix within bucket
        ks[2 * l] = ex;
        ks[2 * l + 1] = ex + s0;
        int gk = b * 128 + 2 * l;
        if (gk < NCNT) rowinfo[gk] = make_uint2(gstart + ex, s0);
        if (gk + 1 < NCNT) rowinfo[gk + 1] = make_uint2(gstart + ex + s0, s1);
    }
    __syncthreads();
    for (int i = threadIdx.x; i < size; i += 256) {
        u32 en = stage[gstart + i];
        u32 kl = en >> 17;
        u32 p = atomicAdd(&ks[kl], 1u);
        csr[gstart + p] = en & 0x1FFFFu;
    }
}

// ---------------- pair-row gather body (r10) -------------------------------
// Lanes 0-31 read row of entry (t+2k), lanes 32-63 row of entry (t+2k+1),
// 8 B/lane: ONE load instruction covers TWO entries at 2x bytes/lane (halves
// load-instruction count AND per-entry latency exposure vs GATHER8).
// Lane accumulates channels (lane&31)*4+{0..3}; halves merged by shfl_xor(32).
#define GATHERP(SRC)                                                          \
    for (u32 base = 0; base < deg; base += 64) {                              \
        int m = (int)min(64u, deg - base);                                    \
        int myidx = (lane < m) ? (int)csr[start + base + lane] : 0;           \
        for (int t = 0; t < m; t += 8) {                                      \
            int e0 = min(t + 0 + half, m - 1), e1 = min(t + 2 + half, m - 1); \
            int e2 = min(t + 4 + half, m - 1), e3 = min(t + 6 + half, m - 1); \
            int r0 = __shfl(myidx, e0), r1 = __shfl(myidx, e1);               \
            int r2 = __shfl(myidx, e2), r3 = __shfl(myidx, e3);               \
            uint2 u0 = ((const uint2*)(SRC + (size_t)r0 * C))[ch];            \
            uint2 u1 = ((const uint2*)(SRC + (size_t)r1 * C))[ch];            \
            uint2 u2 = ((const uint2*)(SRC + (size_t)r2 * C))[ch];            \
            uint2 u3 = ((const uint2*)(SRC + (size_t)r3 * C))[ch];            \
            float m0 = (t + 0 + half < m) ? 1.f : 0.f;                        \
            float m1 = (t + 2 + half < m) ? 1.f : 0.f;                        \
            float m2 = (t + 4 + half < m) ? 1.f : 0.f;                        \
            float m3 = (t + 6 + half < m) ? 1.f : 0.f;                        \
            a0 += m0 * bf2f((u16)(u0.x & 0xffffu)) + m1 * bf2f((u16)(u1.x & 0xffffu)) \
                + m2 * bf2f((u16)(u2.x & 0xffffu)) + m3 * bf2f((u16)(u3.x & 0xffffu)); \
            a1 += m0 * bf2f((u16)(u0.x >> 16)) + m1 * bf2f((u16)(u1.x >> 16)) \
                + m2 * bf2f((u16)(u2.x >> 16)) + m3 * bf2f((u16)(u3.x >> 16)); \
            a2 += m0 * bf2f((u16)(u0.y & 0xffffu)) + m1 * bf2f((u16)(u1.y & 0xffffu)) \
                + m2 * bf2f((u16)(u2.y & 0xffffu)) + m3 * bf2f((u16)(u3.y & 0xffffu)); \
            a3 += m0 * bf2f((u16)(u0.y >> 16)) + m1 * bf2f((u16)(u1.y >> 16)) \
                + m2 * bf2f((u16)(u2.y >> 16)) + m3 * bf2f((u16)(u3.y >> 16)); \
        }                                                                     \
    }                                                                         \
    a0 += __shfl_xor(a0, 32);                                                 \
    a1 += __shfl_xor(a1, 32);                                                 \
    a2 += __shfl_xor(a2, 32);                                                 \
    a3 += __shfl_xor(a3, 32);

// ---------------- edge gather over CSR: 1 edge per wave -------------------
// ef[e] = bf16(B^-1_e * sum xw[nodes of e])
__global__ __launch_bounds__(256) void edge_gather_k(const u16* __restrict__ xw,
                                                     const uint2* __restrict__ rowinfo,
                                                     const u32* __restrict__ csrC,
                                                     u16* __restrict__ ef) {
    int e = blockIdx.x * 4 + (threadIdx.x >> 6);
    if (e >= N_EDGES) return;
    int lane = threadIdx.x & 63;
    int half = lane >> 5, ch = lane & 31;
    uint2 ri = rowinfo[e];
    u32 deg = ri.y;
    u32 start = ri.x;  // absolute position in combined csr
    const u32* csr = csrC;
    float a0 = 0.f, a1 = 0.f, a2 = 0.f, a3 = 0.f;
    GATHERP(xw)
    float sc = deg ? 1.f / (float)deg : 0.f;
    if (lane < 32) {
        uint2 w;
        w.x = (u32)f2bf(a0 * sc) | ((u32)f2bf(a1 * sc) << 16);
        w.y = (u32)f2bf(a2 * sc) | ((u32)f2bf(a3 * sc) << 16);
        ((uint2*)(ef + (size_t)e * C))[ch] = w;
    }
}

// ---------------- node gather over CSR: 1 node per wave -------------------
// out[v] = f32( D^-1_v * sum ef[edges of v] + b )
__global__ __launch_bounds__(256) void node_gather_k(const u16* __restrict__ ef,
                                                     const uint2* __restrict__ rowinfo,
                                                     const u32* __restrict__ csrC,
                                                     const float* __restrict__ bias,
                                                     float* __restrict__ out) {
    int v = blockIdx.x * 4 + (threadIdx.x >> 6);
    if (v >= N_NODES) return;
    int lane = threadIdx.x & 63;
    int half = lane >> 5, ch = lane & 31;
    uint2 ri = rowinfo[N_EDGES + v];
    u32 deg = ri.y;
    u32 start = ri.x;  // absolute position in combined csr
    const u32* csr = csrC;
    float a0 = 0.f, a1 = 0.f, a2 = 0.f, a3 = 0.f;
    GATHERP(ef)
    float sc = deg ? 1.f / (float)deg : 0.f;
    if (lane < 32) {
        float4 bv = *(const float4*)(bias + ch * 4);
        float4 w;
        w.x = a0 * sc + bv.x;
        w.y = a1 * sc + bv.y;
        w.z = a2 * sc + bv.z;
        w.w = a3 * sc + bv.w;
        ((float4*)(out + (size_t)v * C))[ch] = w;
    }
}

extern "C" void kernel_launch(void* const* d_in, const int* in_sizes, int n_in,
                              void* d_out, int out_size, void* d_ws, size_t ws_size,
                              hipStream_t stream) {
    const float* x = (const float*)d_in[0];     // [N_NODES,128] f32
    const int* node_idx = (const int*)d_in[1];  // [2, NNZ] row-major int32
    const int nnz = in_sizes[1] / 2;
    const int* edge_idx = node_idx + nnz;
    const float* W = (const float*)d_in[2];     // [128,128] f32
    const float* bias = (const float*)d_in[3];  // [128] f32
    float* out = (float*)d_out;                 // [N_NODES,128] f32

    int nb1 = (nnz + BCHUNK - 1) / BCHUNK;      // 245 bucketize blocks
    int scanN = NBUCKC * nb1;                   // 287140 count-matrix entries
    int scanBlocks = (scanN + 1023) / 1024;     // 281 (<= 512 for scan_b2)

    // workspace layout (~20.3 MB), all 16B-aligned:
    u16* Wt = (u16*)d_ws;                           // 32 KB
    u16* ef = Wt + 16384;                           // 12.8 MB
    u32* cntM = (u32*)(ef + (size_t)N_EDGES * C);   // scanN u32 (1.15 MB)
    u32* offM = cntM + scanN;                       // scanN u32 (1.15 MB)
    u32* bsum2 = offM + scanN;                      // 512 u32
    uint2* rowinfo = (uint2*)(bsum2 + 512);         // 150000 uint2 (1.2 MB)
    u32* csrC = (u32*)(rowinfo + NCNT);             // 2*nnz u32 (4 MB)

    // d_out (51.2 MB f32) doubles as scratch:
    //   [0, 25.6 MB):    xw bf16        — consumed by edge_gather
    //   [25.6, 29.6 MB): stage (packed) — consumed by bucket_csr_k
    //   (gemm's guarded tail rows may scribble on stage[0..8KB); harmless:
    //    bucket_place_k writes stage AFTER gemm completes.)
    // node_gather then overwrites the whole buffer with the f32 output.
    u16* xw = (u16*)d_out;
    u32* stage = (u32*)((char*)d_out + (size_t)N_NODES * C * 2);

    transpose_w<<<64, 256, 0, stream>>>(W, Wt);
    gemm_k<<<G_GEMM, 256, 0, stream>>>(x, Wt, xw);
    bucket_hist_k<<<nb1, 256, 0, stream>>>(node_idx, edge_idx, cntM, nnz, nb1);
    scan_a2<<<scanBlocks, 256, 0, stream>>>(cntM, offM, bsum2, scanN);
    scan_b2<<<1, 256, 0, stream>>>(bsum2, scanBlocks);
    bucket_place_k<<<nb1, 256, 0, stream>>>(node_idx, edge_idx, offM, bsum2,
                                            stage, nnz, nb1);
    bucket_csr_k<<<NBUCKC, 256, 0, stream>>>(offM, bsum2, stage, csrC, rowinfo,
                                             nnz, nb1);
    // 1 edge/node per wave, 4 waves per block
    edge_gather_k<<<(N_EDGES + 3) / 4, 256, 0, stream>>>(xw, rowinfo, csrC, ef);
    node_gather_k<<<(N_NODES + 3) / 4, 256, 0, stream>>>(ef, rowinfo, csrC, bias, out);
}